// Round 5
// baseline (161.536 us; speedup 1.0000x reference)
//
#include <hip/hip_runtime.h>
#include <hip/hip_bf16.h>

#define CCH 64      // channels
#define NPIX 4096   // 64*64 pooled points

typedef __attribute__((ext_vector_type(8))) short short8;   // 8 bf16 (4 VGPRs)
typedef __attribute__((ext_vector_type(16))) float f32x16;  // MFMA 32x32 accumulator

union U4S8 { uint4 u; short8 s; };

__device__ inline uint32_t pk2bf(float lo, float hi) {
    __hip_bfloat162 h = __float22bfloat162_rn(make_float2(lo, hi));
    return *reinterpret_cast<uint32_t*>(&h);
}

// ---------------------------------------------------------------------------
// Kernel 1: avg-pool 4x4 + 1x1 convs.
//   Q, K: bf16 (b, n, 8)
//   VP  : bf16 packed in PV A-fragment order (see attn kernel)
// Conv strategy: xd staged [point][channel] in LDS, register-cached per
// thread (16 x ds_read_b128); weights read wave-uniformly from global
// (readfirstlane-forced -> s_load, SGPR operands). No per-FMA LDS traffic.
// ---------------------------------------------------------------------------
__global__ __launch_bounds__(256) void pool_qkv_kernel(
    const float* __restrict__ x,
    const float* __restrict__ Wq, const float* __restrict__ bq,
    const float* __restrict__ Wk, const float* __restrict__ bk,
    const float* __restrict__ Wv, const float* __restrict__ bv,
    __hip_bfloat16* __restrict__ Qo, __hip_bfloat16* __restrict__ Ko,
    __hip_bfloat16* __restrict__ VPo)
{
    const int b    = blockIdx.x >> 6;
    const int ph   = blockIdx.x & 63;
    const int t    = threadIdx.x;
    const int lane = t & 63;

    __shared__ float xd[64][68];   // [point][channel]; row = 272 B (16B-aligned)

    // ---- pooling: wave w4 covers 16 points x 4 rows ----
    const int w4 = t >> 6;
    const int r  = lane & 3;
    const int pw = w4 * 16 + (lane >> 2);

    const float* xb = x + (size_t)b * CCH * 65536 + (size_t)(ph*4 + r) * 256 + pw*4;
    for (int c = 0; c < CCH; ++c) {
        float4 v = *(const float4*)(xb + (size_t)c * 65536);
        float s = v.x + v.y + v.z + v.w;
        s += __shfl_xor(s, 1);
        s += __shfl_xor(s, 2);
        if (r == 0) xd[pw][c] = s * 0.0625f;
    }
    __syncthreads();

    // ---- conv: register-cache the point's 64 channels ----
    const int pw2 = t & 63;
    const int g   = __builtin_amdgcn_readfirstlane(t >> 6);   // wave-uniform group

    float xr[64];
    #pragma unroll
    for (int c4 = 0; c4 < 16; ++c4) {
        float4 v = *(const float4*)&xd[pw2][c4*4];
        xr[c4*4+0] = v.x; xr[c4*4+1] = v.y; xr[c4*4+2] = v.z; xr[c4*4+3] = v.w;
    }

    const int i = ph * 64 + pw2;
    #pragma unroll 1
    for (int u = 0; u < 20; ++u) {
        const int oc = g*20 + u;             // wave-uniform
        const float* wrow; float bias;
        if (oc < 8)       { wrow = Wq + oc*CCH;      bias = bq[oc]; }
        else if (oc < 16) { wrow = Wk + (oc-8)*CCH;  bias = bk[oc-8]; }
        else              { wrow = Wv + (oc-16)*CCH; bias = bv[oc-16]; }
        float sum = bias;
        #pragma unroll
        for (int c = 0; c < CCH; ++c) sum += wrow[c] * xr[c];

        if (oc < 8)       Qo[((size_t)b*NPIX + i)*8  + oc]     = __float2bfloat16(sum);
        else if (oc < 16) Ko[((size_t)b*NPIX + i)*8  + (oc-8)] = __float2bfloat16(sum);
        else {
            const int c  = oc - 16;
            const int chg = i >> 5, s1 = (i>>4)&1, h2 = (i>>3)&1, el = i&7;
            const int ct = c >> 5;
            VPo[(((size_t)b*512 + (size_t)((chg*2 + s1)*2 + ct))*512)
                + (h2*32 + (c&31))*8 + el] = __float2bfloat16(sum);
        }
    }
}

// ---------------------------------------------------------------------------
// Kernel 2: flash attention. 1024 blocks (xcd-mapped: b = blk&7), 256 thr =
// 4 waves = 4 kv-quarters; each block covers 32 queries.
//   S^T = mfma(K_frag, Q_frag): lane (q=l&31) holds 16 of 32 kv scores.
//   PV  = mfma(V_frag(A, packed coalesced), P_frag(B via half-exchange)):
//         D[row=c][col=q], all 16 acc values belong to lane's own query.
// 4-way kv merge through LDS at the end.
// ---------------------------------------------------------------------------
__global__ __launch_bounds__(256, 4) void attn_kernel(
    const __hip_bfloat16* __restrict__ Q, const __hip_bfloat16* __restrict__ K,
    const __hip_bfloat16* __restrict__ VP, float* __restrict__ OS)
{
    const int bb   = blockIdx.x;
    const int b    = bb & 7;          // XCD-locality: batch per XCD
    const int qg   = bb >> 3;         // 0..127
    const int i0   = qg * 32;
    const int t    = threadIdx.x;
    const int lane = t & 63;
    const int kvq  = t >> 6;          // wave = kv quarter
    const int l31  = lane & 31;
    const int hi   = lane >> 5;

    __shared__ float tiles[4][64][33];
    __shared__ float ml[4][2][32];
    __shared__ float fs[4][32];
    __shared__ float ils[32];

    // Q fragment (B operand): hi=0 lanes hold Q[q=i0+l31][d=0..7], hi=1 zero
    U4S8 qf;
    if (hi == 0) qf.u = *(const uint4*)(Q + ((size_t)b*NPIX + i0 + l31)*8);
    else         qf.u = make_uint4(0,0,0,0);

    f32x16 acc0, acc1, zacc;
    #pragma unroll
    for (int r = 0; r < 16; ++r) { acc0[r] = 0.f; acc1[r] = 0.f; zacc[r] = 0.f; }
    float m = -1e30f, l = 0.f;

    const __hip_bfloat16* Kb  = K  + (size_t)b*NPIX*8;
    const __hip_bfloat16* VPb = VP + (size_t)b*512*512;   // 512 frags x 512 bf16

    auto ldK = [&](int kv) {
        U4S8 r;
        if (hi == 0) r.u = *(const uint4*)(Kb + (size_t)(kv + l31)*8);
        else         r.u = make_uint4(0,0,0,0);
        return r;
    };
    auto ldVP = [&](int chg, int s1, int ct) {
        U4S8 r;
        r.u = *(const uint4*)(VPb + ((size_t)((chg*2 + s1)*2 + ct))*512 + lane*8);
        return r;
    };

    int kv0 = kvq * 1024;
    // prefetch chunk 0
    U4S8 kf = ldK(kv0);
    U4S8 v00 = ldVP(kv0>>5, 0, 0), v10 = ldVP(kv0>>5, 0, 1);
    U4S8 v01 = ldVP(kv0>>5, 1, 0), v11 = ldVP(kv0>>5, 1, 1);

    #pragma unroll 1
    for (int ch = 0; ch < 32; ++ch) {
        U4S8 ckf = kf, cv00 = v00, cv01 = v01, cv10 = v10, cv11 = v11;
        const int nkv0 = kv0 + 32;
        // prefetch next chunk (reads past quarter stay inside d_ws; unused on last iter)
        kf  = ldK(nkv0);
        v00 = ldVP(nkv0>>5, 0, 0); v10 = ldVP(nkv0>>5, 0, 1);
        v01 = ldVP(nkv0>>5, 1, 0); v11 = ldVP(nkv0>>5, 1, 1);

        // S^T: lane holds q=l31, kv rows (r&3)+8*(r>>2)+4*hi of this 32-chunk
        f32x16 s = __builtin_amdgcn_mfma_f32_32x32x16_bf16(ckf.s, qf.s, zacc, 0, 0, 0);

        float mx = fmaxf(s[0], s[1]);
        #pragma unroll
        for (int r = 2; r < 16; ++r) mx = fmaxf(mx, s[r]);
        mx = fmaxf(mx, __shfl_xor(mx, 32));

        // deferred rescale (T13): all acc cols are lane's own query -> plain scale
        if (!__all(mx <= m + 8.f)) {
            float mnew = fmaxf(m, mx);
            float sc = __expf(m - mnew);
            l *= sc; m = mnew;
            #pragma unroll
            for (int r = 0; r < 16; ++r) { acc0[r] *= sc; acc1[r] *= sc; }
        }

        float p[16];
        float ssum = 0.f;
        #pragma unroll
        for (int r = 0; r < 16; ++r) { p[r] = __expf(s[r] - m); ssum += p[r]; }
        ssum += __shfl_xor(ssum, 32);
        l += ssum;

        // B-operand P fragments: lane (l31,hi) needs P[q=l31][kv=16s+8hi+j].
        // Own p[] holds kv {4hi+0..3, 8+4hi+0..3, 16+..., 24+...}; partner half
        // supplies the other quads via shfl_xor(32).
        uint32_t W01 = pk2bf(p[0],  p[1]),  W23 = pk2bf(p[2],  p[3]);
        uint32_t W45 = pk2bf(p[4],  p[5]),  W67 = pk2bf(p[6],  p[7]);
        uint32_t W89 = pk2bf(p[8],  p[9]),  Wab = pk2bf(p[10], p[11]);
        uint32_t Wcd = pk2bf(p[12], p[13]), Wef = pk2bf(p[14], p[15]);
        uint32_t W45p = (uint32_t)__shfl_xor((int)W45, 32);
        uint32_t W67p = (uint32_t)__shfl_xor((int)W67, 32);
        uint32_t W01p = (uint32_t)__shfl_xor((int)W01, 32);
        uint32_t W23p = (uint32_t)__shfl_xor((int)W23, 32);
        uint32_t Wcdp = (uint32_t)__shfl_xor((int)Wcd, 32);
        uint32_t Wefp = (uint32_t)__shfl_xor((int)Wef, 32);
        uint32_t W89p = (uint32_t)__shfl_xor((int)W89, 32);
        uint32_t Wabp = (uint32_t)__shfl_xor((int)Wab, 32);
        U4S8 pb0, pb1;
        pb0.u.x = hi ? W45p : W01;   pb0.u.y = hi ? W67p : W23;
        pb0.u.z = hi ? W45  : W01p;  pb0.u.w = hi ? W67  : W23p;
        pb1.u.x = hi ? Wcdp : W89;   pb1.u.y = hi ? Wefp : Wab;
        pb1.u.z = hi ? Wcd  : W89p;  pb1.u.w = hi ? Wef  : Wabp;

        acc0 = __builtin_amdgcn_mfma_f32_32x32x16_bf16(cv00.s, pb0.s, acc0, 0, 0, 0);
        acc1 = __builtin_amdgcn_mfma_f32_32x32x16_bf16(cv10.s, pb0.s, acc1, 0, 0, 0);
        acc0 = __builtin_amdgcn_mfma_f32_32x32x16_bf16(cv01.s, pb1.s, acc0, 0, 0, 0);
        acc1 = __builtin_amdgcn_mfma_f32_32x32x16_bf16(cv11.s, pb1.s, acc1, 0, 0, 0);

        kv0 = nkv0;
    }

    // ---- 4-way kv merge ----
    #pragma unroll
    for (int r = 0; r < 16; ++r) {
        const int cr = (r&3) + 8*(r>>2) + 4*hi;
        tiles[kvq][cr]     [l31] = acc0[r];
        tiles[kvq][cr + 32][l31] = acc1[r];
    }
    if (hi == 0) { ml[kvq][0][l31] = m; ml[kvq][1][l31] = l; }
    __syncthreads();

    if (t < 32) {
        float m0 = ml[0][0][t], m1 = ml[1][0][t], m2 = ml[2][0][t], m3 = ml[3][0][t];
        float ms = fmaxf(fmaxf(m0, m1), fmaxf(m2, m3));
        float f0 = __expf(m0-ms), f1 = __expf(m1-ms), f2 = __expf(m2-ms), f3 = __expf(m3-ms);
        fs[0][t] = f0; fs[1][t] = f1; fs[2][t] = f2; fs[3][t] = f3;
        ils[t] = 1.f / (ml[0][1][t]*f0 + ml[1][1][t]*f1 + ml[2][1][t]*f2 + ml[3][1][t]*f3);
    }
    __syncthreads();

    // combine + write: OS (b, c, n); thread -> (c = t>>2, 8 queries)
    float* outp = OS + (size_t)b*CCH*NPIX + i0;
    const int c  = t >> 2;
    const int q8 = (t & 3) * 8;
    float o[8];
    #pragma unroll
    for (int j = 0; j < 8; ++j) {
        const int q = q8 + j;
        float v = tiles[0][c][q]*fs[0][q] + tiles[1][c][q]*fs[1][q]
                + tiles[2][c][q]*fs[2][q] + tiles[3][c][q]*fs[3][q];
        o[j] = v * ils[q];
    }
    *(float4*)(outp + (size_t)c*NPIX + q8)     = make_float4(o[0], o[1], o[2], o[3]);
    *(float4*)(outp + (size_t)c*NPIX + q8 + 4) = make_float4(o[4], o[5], o[6], o[7]);
}

// ---------------------------------------------------------------------------
// Kernel 3: bilinear x4 upsample (align_corners=True) + gamma*up + x
// ---------------------------------------------------------------------------
__global__ __launch_bounds__(256) void upsample_add_kernel(
    const float* __restrict__ OS, const float* __restrict__ x,
    const float* __restrict__ gamma, float* __restrict__ out)
{
    const size_t idx = (size_t)blockIdx.x * 256 + threadIdx.x;
    const float g = gamma[0];
    const int w  = idx & 255;
    const int h  = (int)((idx >> 8) & 255);
    const size_t bc = idx >> 16;

    const float scale = 63.0f / 255.0f;
    float fh = h * scale; int h0 = (int)fh; float fy = fh - (float)h0; int h1 = min(h0+1, 63);
    float fw = w * scale; int w0 = (int)fw; float fx = fw - (float)w0; int w1 = min(w0+1, 63);

    const float* osp = OS + bc * (size_t)NPIX;
    float v00 = osp[h0*64+w0], v01 = osp[h0*64+w1];
    float v10 = osp[h1*64+w0], v11 = osp[h1*64+w1];
    float vt = v00 + (v01 - v00) * fx;
    float vb = v10 + (v11 - v10) * fx;
    float up = vt + (vb - vt) * fy;
    out[idx] = g * up + x[idx];
}

// ---------------------------------------------------------------------------
extern "C" void kernel_launch(void* const* d_in, const int* in_sizes, int n_in,
                              void* d_out, int out_size, void* d_ws, size_t ws_size,
                              hipStream_t stream) {
    const float* x     = (const float*)d_in[0];
    const float* Wq    = (const float*)d_in[1];
    const float* bq    = (const float*)d_in[2];
    const float* Wk    = (const float*)d_in[3];
    const float* bk    = (const float*)d_in[4];
    const float* Wv    = (const float*)d_in[5];
    const float* bv    = (const float*)d_in[6];
    const float* gamma = (const float*)d_in[7];
    float* out = (float*)d_out;

    char* ws = (char*)d_ws;
    __hip_bfloat16* Qb = (__hip_bfloat16*)(ws);                      // 512 KB
    __hip_bfloat16* Kb = (__hip_bfloat16*)(ws + (size_t)( 512<<10)); // 512 KB
    __hip_bfloat16* VP = (__hip_bfloat16*)(ws + (size_t)(1024<<10)); // 4 MB packed
    float*          OS = (float*)         (ws + (size_t)(5120<<10)); // 8 MB

    pool_qkv_kernel<<<512, 256, 0, stream>>>(x, Wq, bq, Wk, bk, Wv, bv, Qb, Kb, VP);
    attn_kernel<<<1024, 256, 0, stream>>>(Qb, Kb, VP, OS);
    const size_t total = (size_t)8 * 64 * 256 * 256;
    upsample_add_kernel<<<(int)(total / 256), 256, 0, stream>>>(OS, x, gamma, out);
}

// Round 6
// 151.471 us; speedup vs baseline: 1.0664x; 1.0664x over previous
//
#include <hip/hip_runtime.h>
#include <hip/hip_bf16.h>

#define CCH 64      // channels
#define NPIX 4096   // 64*64 pooled points

typedef __attribute__((ext_vector_type(8))) short short8;   // 8 bf16 (4 VGPRs)
typedef __attribute__((ext_vector_type(16))) float f32x16;  // MFMA 32x32 accumulator

union U4S8 { uint4 u; short8 s; };

__device__ inline uint32_t pk2bf(float lo, float hi) {
    __hip_bfloat162 h = __float22bfloat162_rn(make_float2(lo, hi));
    return *reinterpret_cast<uint32_t*>(&h);
}

// ---------------------------------------------------------------------------
// Kernel 1a: avg-pool 4x4 only.  x (b,c,256,256) -> xd (b, point, ch) fp32.
// grid = 8b x 4cg x 64ph = 2048 blocks, 256 thr.
// Wave w covers channels cg*16 + w*4 .. +4, lanes = 64 points of row ph.
// Reads: 16 independent float4 loads/thread, each wave-instr 1KB contiguous.
// Writes: LDS-transposed so each thread stores one float4 (full 64B lines).
// ---------------------------------------------------------------------------
__global__ __launch_bounds__(256) void pool_kernel(
    const float* __restrict__ x, float* __restrict__ xd)
{
    const int blk  = blockIdx.x;
    const int ph   = blk & 63;
    const int cg   = (blk >> 6) & 3;
    const int b    = blk >> 8;
    const int t    = threadIdx.x;
    const int lane = t & 63;
    const int w    = t >> 6;

    __shared__ float xdl[64][20];   // [point][16 ch + pad]

    float val[4];
    #pragma unroll
    for (int j = 0; j < 4; ++j) {
        const int c = cg*16 + w*4 + j;
        const float* xp = x + ((size_t)(b*CCH + c)*256 + ph*4)*256 + lane*4;
        float4 a0 = *(const float4*)(xp);
        float4 a1 = *(const float4*)(xp + 256);
        float4 a2 = *(const float4*)(xp + 512);
        float4 a3 = *(const float4*)(xp + 768);
        val[j] = (a0.x+a0.y+a0.z+a0.w + a1.x+a1.y+a1.z+a1.w
                + a2.x+a2.y+a2.z+a2.w + a3.x+a3.y+a3.z+a3.w) * 0.0625f;
    }
    #pragma unroll
    for (int j = 0; j < 4; ++j) xdl[lane][w*4 + j] = val[j];
    __syncthreads();

    const int p = t >> 2, c4 = t & 3;
    float4 v = *(const float4*)&xdl[p][c4*4];
    *(float4*)(xd + ((size_t)b*NPIX + ph*64 + p)*CCH + cg*16 + c4*4) = v;
}

// ---------------------------------------------------------------------------
// Kernel 1b: 1x1 convs from xd.  512 blocks x 256 thr, 2 waves/EU min
// (explicit VGPR budget so xr[64] stays in registers — round-5 spilled at
// the default occupancy target).  Weights via wave-uniform s_load (SGPRs).
//   Q, K: bf16 (b, n, 8);  VP: bf16 packed in PV A-fragment order.
// ---------------------------------------------------------------------------
__global__ __launch_bounds__(256, 2) void conv_kernel(
    const float* __restrict__ xd,
    const float* __restrict__ Wq, const float* __restrict__ bq,
    const float* __restrict__ Wk, const float* __restrict__ bk,
    const float* __restrict__ Wv, const float* __restrict__ bv,
    __hip_bfloat16* __restrict__ Qo, __hip_bfloat16* __restrict__ Ko,
    __hip_bfloat16* __restrict__ VPo)
{
    const int blk = blockIdx.x;
    const int b   = blk >> 6;
    const int i   = (blk & 63) * 64 + (threadIdx.x & 63);
    const int g   = __builtin_amdgcn_readfirstlane(threadIdx.x >> 6);

    float xr[64];
    const float* xp = xd + ((size_t)b*NPIX + i)*CCH;
    #pragma unroll
    for (int c4 = 0; c4 < 16; ++c4) {
        float4 v = *(const float4*)(xp + c4*4);
        xr[c4*4+0] = v.x; xr[c4*4+1] = v.y; xr[c4*4+2] = v.z; xr[c4*4+3] = v.w;
    }

    #pragma unroll 1
    for (int u = 0; u < 20; ++u) {
        const int oc = g*20 + u;             // wave-uniform
        const float* wrow; float bias;
        if (oc < 8)       { wrow = Wq + oc*CCH;      bias = bq[oc]; }
        else if (oc < 16) { wrow = Wk + (oc-8)*CCH;  bias = bk[oc-8]; }
        else              { wrow = Wv + (oc-16)*CCH; bias = bv[oc-16]; }
        float sum = bias;
        #pragma unroll
        for (int c = 0; c < CCH; ++c) sum += wrow[c] * xr[c];

        if (oc < 8)       Qo[((size_t)b*NPIX + i)*8  + oc]     = __float2bfloat16(sum);
        else if (oc < 16) Ko[((size_t)b*NPIX + i)*8  + (oc-8)] = __float2bfloat16(sum);
        else {
            const int c  = oc - 16;
            const int chg = i >> 5, s1 = (i>>4)&1, h2 = (i>>3)&1, el = i&7;
            const int ct = c >> 5;
            VPo[(((size_t)b*512 + (size_t)((chg*2 + s1)*2 + ct))*512)
                + (h2*32 + (c&31))*8 + el] = __float2bfloat16(sum);
        }
    }
}

// ---------------------------------------------------------------------------
// Kernel 2: flash attention. 1024 blocks (xcd-mapped: b = blk&7), 256 thr =
// 4 waves = 4 kv-quarters; each block covers 32 queries.
//   S^T = mfma(K_frag, Q_frag): lane (q=l&31) holds 16 of 32 kv scores.
//   PV  = mfma(V_frag(A, packed coalesced), P_frag(B via half-exchange)):
//         D[row=c][col=q], all 16 acc values belong to lane's own query.
// 4-way kv merge through LDS at the end.
// ---------------------------------------------------------------------------
__global__ __launch_bounds__(256, 4) void attn_kernel(
    const __hip_bfloat16* __restrict__ Q, const __hip_bfloat16* __restrict__ K,
    const __hip_bfloat16* __restrict__ VP, float* __restrict__ OS)
{
    const int bb   = blockIdx.x;
    const int b    = bb & 7;          // XCD-locality: batch per XCD
    const int qg   = bb >> 3;         // 0..127
    const int i0   = qg * 32;
    const int t    = threadIdx.x;
    const int lane = t & 63;
    const int kvq  = t >> 6;          // wave = kv quarter
    const int l31  = lane & 31;
    const int hi   = lane >> 5;

    __shared__ float tiles[4][64][33];
    __shared__ float ml[4][2][32];
    __shared__ float fs[4][32];
    __shared__ float ils[32];

    // Q fragment (B operand): hi=0 lanes hold Q[q=i0+l31][d=0..7], hi=1 zero
    U4S8 qf;
    if (hi == 0) qf.u = *(const uint4*)(Q + ((size_t)b*NPIX + i0 + l31)*8);
    else         qf.u = make_uint4(0,0,0,0);

    f32x16 acc0, acc1, zacc;
    #pragma unroll
    for (int r = 0; r < 16; ++r) { acc0[r] = 0.f; acc1[r] = 0.f; zacc[r] = 0.f; }
    float m = -1e30f, l = 0.f;

    const __hip_bfloat16* Kb  = K  + (size_t)b*NPIX*8;
    const __hip_bfloat16* VPb = VP + (size_t)b*512*512;   // 512 frags x 512 bf16

    auto ldK = [&](int kv) {
        U4S8 r;
        if (hi == 0) r.u = *(const uint4*)(Kb + (size_t)(kv + l31)*8);
        else         r.u = make_uint4(0,0,0,0);
        return r;
    };
    auto ldVP = [&](int chg, int s1, int ct) {
        U4S8 r;
        r.u = *(const uint4*)(VPb + ((size_t)((chg*2 + s1)*2 + ct))*512 + lane*8);
        return r;
    };

    int kv0 = kvq * 1024;
    // prefetch chunk 0
    U4S8 kf = ldK(kv0);
    U4S8 v00 = ldVP(kv0>>5, 0, 0), v10 = ldVP(kv0>>5, 0, 1);
    U4S8 v01 = ldVP(kv0>>5, 1, 0), v11 = ldVP(kv0>>5, 1, 1);

    #pragma unroll 1
    for (int ch = 0; ch < 32; ++ch) {
        U4S8 ckf = kf, cv00 = v00, cv01 = v01, cv10 = v10, cv11 = v11;
        const int nkv0 = kv0 + 32;
        // prefetch next chunk (reads past quarter stay inside d_ws; unused on last iter)
        kf  = ldK(nkv0);
        v00 = ldVP(nkv0>>5, 0, 0); v10 = ldVP(nkv0>>5, 0, 1);
        v01 = ldVP(nkv0>>5, 1, 0); v11 = ldVP(nkv0>>5, 1, 1);

        // S^T: lane holds q=l31, kv rows (r&3)+8*(r>>2)+4*hi of this 32-chunk
        f32x16 s = __builtin_amdgcn_mfma_f32_32x32x16_bf16(ckf.s, qf.s, zacc, 0, 0, 0);

        float mx = fmaxf(s[0], s[1]);
        #pragma unroll
        for (int r = 2; r < 16; ++r) mx = fmaxf(mx, s[r]);
        mx = fmaxf(mx, __shfl_xor(mx, 32));

        // deferred rescale (T13): all acc cols are lane's own query -> plain scale
        if (!__all(mx <= m + 8.f)) {
            float mnew = fmaxf(m, mx);
            float sc = __expf(m - mnew);
            l *= sc; m = mnew;
            #pragma unroll
            for (int r = 0; r < 16; ++r) { acc0[r] *= sc; acc1[r] *= sc; }
        }

        float p[16];
        float ssum = 0.f;
        #pragma unroll
        for (int r = 0; r < 16; ++r) { p[r] = __expf(s[r] - m); ssum += p[r]; }
        ssum += __shfl_xor(ssum, 32);
        l += ssum;

        // B-operand P fragments: lane (l31,hi) needs P[q=l31][kv=16s+8hi+j].
        // Own p[] holds kv {4hi+0..3, 8+4hi+0..3, 16+..., 24+...}; partner half
        // supplies the other quads via shfl_xor(32).
        uint32_t W01 = pk2bf(p[0],  p[1]),  W23 = pk2bf(p[2],  p[3]);
        uint32_t W45 = pk2bf(p[4],  p[5]),  W67 = pk2bf(p[6],  p[7]);
        uint32_t W89 = pk2bf(p[8],  p[9]),  Wab = pk2bf(p[10], p[11]);
        uint32_t Wcd = pk2bf(p[12], p[13]), Wef = pk2bf(p[14], p[15]);
        uint32_t W45p = (uint32_t)__shfl_xor((int)W45, 32);
        uint32_t W67p = (uint32_t)__shfl_xor((int)W67, 32);
        uint32_t W01p = (uint32_t)__shfl_xor((int)W01, 32);
        uint32_t W23p = (uint32_t)__shfl_xor((int)W23, 32);
        uint32_t Wcdp = (uint32_t)__shfl_xor((int)Wcd, 32);
        uint32_t Wefp = (uint32_t)__shfl_xor((int)Wef, 32);
        uint32_t W89p = (uint32_t)__shfl_xor((int)W89, 32);
        uint32_t Wabp = (uint32_t)__shfl_xor((int)Wab, 32);
        U4S8 pb0, pb1;
        pb0.u.x = hi ? W45p : W01;   pb0.u.y = hi ? W67p : W23;
        pb0.u.z = hi ? W45  : W01p;  pb0.u.w = hi ? W67  : W23p;
        pb1.u.x = hi ? Wcdp : W89;   pb1.u.y = hi ? Wefp : Wab;
        pb1.u.z = hi ? Wcd  : W89p;  pb1.u.w = hi ? Wef  : Wabp;

        acc0 = __builtin_amdgcn_mfma_f32_32x32x16_bf16(cv00.s, pb0.s, acc0, 0, 0, 0);
        acc1 = __builtin_amdgcn_mfma_f32_32x32x16_bf16(cv10.s, pb0.s, acc1, 0, 0, 0);
        acc0 = __builtin_amdgcn_mfma_f32_32x32x16_bf16(cv01.s, pb1.s, acc0, 0, 0, 0);
        acc1 = __builtin_amdgcn_mfma_f32_32x32x16_bf16(cv11.s, pb1.s, acc1, 0, 0, 0);

        kv0 = nkv0;
    }

    // ---- 4-way kv merge ----
    #pragma unroll
    for (int r = 0; r < 16; ++r) {
        const int cr = (r&3) + 8*(r>>2) + 4*hi;
        tiles[kvq][cr]     [l31] = acc0[r];
        tiles[kvq][cr + 32][l31] = acc1[r];
    }
    if (hi == 0) { ml[kvq][0][l31] = m; ml[kvq][1][l31] = l; }
    __syncthreads();

    if (t < 32) {
        float m0 = ml[0][0][t], m1 = ml[1][0][t], m2 = ml[2][0][t], m3 = ml[3][0][t];
        float ms = fmaxf(fmaxf(m0, m1), fmaxf(m2, m3));
        float f0 = __expf(m0-ms), f1 = __expf(m1-ms), f2 = __expf(m2-ms), f3 = __expf(m3-ms);
        fs[0][t] = f0; fs[1][t] = f1; fs[2][t] = f2; fs[3][t] = f3;
        ils[t] = 1.f / (ml[0][1][t]*f0 + ml[1][1][t]*f1 + ml[2][1][t]*f2 + ml[3][1][t]*f3);
    }
    __syncthreads();

    // combine + write: OS (b, c, n); thread -> (c = t>>2, 8 queries)
    float* outp = OS + (size_t)b*CCH*NPIX + i0;
    const int c  = t >> 2;
    const int q8 = (t & 3) * 8;
    float o[8];
    #pragma unroll
    for (int j = 0; j < 8; ++j) {
        const int q = q8 + j;
        float v = tiles[0][c][q]*fs[0][q] + tiles[1][c][q]*fs[1][q]
                + tiles[2][c][q]*fs[2][q] + tiles[3][c][q]*fs[3][q];
        o[j] = v * ils[q];
    }
    *(float4*)(outp + (size_t)c*NPIX + q8)     = make_float4(o[0], o[1], o[2], o[3]);
    *(float4*)(outp + (size_t)c*NPIX + q8 + 4) = make_float4(o[4], o[5], o[6], o[7]);
}

// ---------------------------------------------------------------------------
// Kernel 3: bilinear x4 upsample (align_corners=True) + gamma*up + x
// ---------------------------------------------------------------------------
__global__ __launch_bounds__(256) void upsample_add_kernel(
    const float* __restrict__ OS, const float* __restrict__ x,
    const float* __restrict__ gamma, float* __restrict__ out)
{
    const size_t idx = (size_t)blockIdx.x * 256 + threadIdx.x;
    const float g = gamma[0];
    const int w  = idx & 255;
    const int h  = (int)((idx >> 8) & 255);
    const size_t bc = idx >> 16;

    const float scale = 63.0f / 255.0f;
    float fh = h * scale; int h0 = (int)fh; float fy = fh - (float)h0; int h1 = min(h0+1, 63);
    float fw = w * scale; int w0 = (int)fw; float fx = fw - (float)w0; int w1 = min(w0+1, 63);

    const float* osp = OS + bc * (size_t)NPIX;
    float v00 = osp[h0*64+w0], v01 = osp[h0*64+w1];
    float v10 = osp[h1*64+w0], v11 = osp[h1*64+w1];
    float vt = v00 + (v01 - v00) * fx;
    float vb = v10 + (v11 - v10) * fx;
    float up = vt + (vb - vt) * fy;
    out[idx] = g * up + x[idx];
}

// ---------------------------------------------------------------------------
extern "C" void kernel_launch(void* const* d_in, const int* in_sizes, int n_in,
                              void* d_out, int out_size, void* d_ws, size_t ws_size,
                              hipStream_t stream) {
    const float* x     = (const float*)d_in[0];
    const float* Wq    = (const float*)d_in[1];
    const float* bq    = (const float*)d_in[2];
    const float* Wk    = (const float*)d_in[3];
    const float* bk    = (const float*)d_in[4];
    const float* Wv    = (const float*)d_in[5];
    const float* bv    = (const float*)d_in[6];
    const float* gamma = (const float*)d_in[7];
    float* out = (float*)d_out;

    char* ws = (char*)d_ws;
    __hip_bfloat16* Qb = (__hip_bfloat16*)(ws);                      // 512 KB
    __hip_bfloat16* Kb = (__hip_bfloat16*)(ws + (size_t)( 512<<10)); // 512 KB
    __hip_bfloat16* VP = (__hip_bfloat16*)(ws + (size_t)(1024<<10)); // 4 MB packed
    float*          OS = (float*)         (ws + (size_t)(5120<<10)); // 8 MB
    float*          XD = OS;   // xd aliases OS: dead before attn writes OS

    pool_kernel<<<2048, 256, 0, stream>>>(x, XD);
    conv_kernel<<<512, 256, 0, stream>>>(XD, Wq, bq, Wk, bk, Wv, bv, Qb, Kb, VP);
    attn_kernel<<<1024, 256, 0, stream>>>(Qb, Kb, VP, OS);
    const size_t total = (size_t)8 * 64 * 256 * 256;
    upsample_add_kernel<<<(int)(total / 256), 256, 0, stream>>>(OS, x, gamma, out);
}

// Round 7
// 132.080 us; speedup vs baseline: 1.2230x; 1.1468x over previous
//
#include <hip/hip_runtime.h>
#include <hip/hip_bf16.h>

#define CCH 64      // channels
#define NPIX 4096   // 64*64 pooled points

typedef __attribute__((ext_vector_type(8))) short short8;   // 8 bf16 (4 VGPRs)
typedef __attribute__((ext_vector_type(16))) float f32x16;  // MFMA 32x32 accumulator

union U4S8 { uint4 u; short8 s; };

__device__ inline uint32_t pk2bf(float lo, float hi) {
    __hip_bfloat162 h = __float22bfloat162_rn(make_float2(lo, hi));
    return *reinterpret_cast<uint32_t*>(&h);
}

// ---------------------------------------------------------------------------
// Kernel 1: fused avg-pool 4x4 + 1x1 convs via MFMA.
// grid = 8 b x 64 pooled-rows = 512 blocks (2/CU), 256 thr = 4 waves.
// Pool: wave w loads channels w*16..+15, 4 input rows, 64 pooled cols ->
//       LDS xdt[64 pt][72 ch] bf16 (pad 72 keeps ds_read_b128 <=4-way).
// Conv: out[oc, pt] = W[oc,c] . xd[c,pt] + b  as 32x32x16 bf16 MFMA,
//       A = W fragments (global, L2-hot), B = xdt fragments.
//       wave: ptt = w&1 (32 points); w<2 -> oc-tiles {0,1}, w>=2 -> {2}.
//   Q, K: bf16 (b, n, 8);  VP: bf16 packed in PV A-fragment order.
// ---------------------------------------------------------------------------
__global__ __launch_bounds__(256, 2) void pool_conv_kernel(
    const float* __restrict__ x,
    const float* __restrict__ Wq, const float* __restrict__ bq,
    const float* __restrict__ Wk, const float* __restrict__ bk,
    const float* __restrict__ Wv, const float* __restrict__ bv,
    __hip_bfloat16* __restrict__ Qo, __hip_bfloat16* __restrict__ Ko,
    __hip_bfloat16* __restrict__ VPo)
{
    const int blk  = blockIdx.x;
    const int b    = blk >> 6;
    const int ptg  = blk & 63;           // pooled row index
    const int t    = threadIdx.x;
    const int lane = t & 63;
    const int w    = t >> 6;
    const int l31  = lane & 31;
    const int hi   = lane >> 5;

    __shared__ __align__(16) __hip_bfloat16 xdt[64][72];   // [pt][ch]
    __shared__ float sbias[96];

    if (t < 96) {
        float v = 0.f;
        if (t < 8)       v = bq[t];
        else if (t < 16) v = bk[t-8];
        else if (t < 80) v = bv[t-16];
        sbias[t] = v;
    }

    // ---- pooling: lane = pooled col, 4 input rows summed ----
    const float* xbase = x + (size_t)(b*CCH)*65536 + (size_t)(ptg*4)*256 + lane*4;
    #pragma unroll 4
    for (int cc = 0; cc < 16; ++cc) {
        const int c = w*16 + cc;
        const float* xp = xbase + (size_t)c*65536;
        float4 v0 = *(const float4*)(xp);
        float4 v1 = *(const float4*)(xp + 256);
        float4 v2 = *(const float4*)(xp + 512);
        float4 v3 = *(const float4*)(xp + 768);
        float s = (v0.x+v0.y+v0.z+v0.w) + (v1.x+v1.y+v1.z+v1.w)
                + (v2.x+v2.y+v2.z+v2.w) + (v3.x+v3.y+v3.z+v3.w);
        xdt[lane][c] = __float2bfloat16(s * 0.0625f);
    }

    // ---- W fragments (A operand): lane(l31,hi) holds W[oct*32+l31][kt*16+8hi+e]
    const int  ptt  = w & 1;
    const int  octA = (w < 2) ? 0 : 2;
    const bool hasB = (w < 2);           // second oc-tile (oct=1)

    short8 wfA[4], wfB[4];
    auto loadW = [&](int oct, short8* wf) {
        const int row = oct*32 + l31;
        const float* wr = nullptr;
        if (row < 8)       wr = Wq + row*CCH;
        else if (row < 16) wr = Wk + (row-8)*CCH;
        else if (row < 80) wr = Wv + (row-16)*CCH;
        #pragma unroll
        for (int kt = 0; kt < 4; ++kt) {
            U4S8 f;
            if (wr) {
                const int c0 = kt*16 + hi*8;
                float4 a = *(const float4*)(wr + c0);
                float4 d = *(const float4*)(wr + c0 + 4);
                f.u.x = pk2bf(a.x, a.y); f.u.y = pk2bf(a.z, a.w);
                f.u.z = pk2bf(d.x, d.y); f.u.w = pk2bf(d.z, d.w);
            } else {
                f.u = make_uint4(0,0,0,0);
            }
            wf[kt] = f.s;
        }
    };
    loadW(octA, wfA);
    if (hasB) loadW(1, wfB);

    __syncthreads();

    // ---- B fragments from LDS + MFMA ----
    short8 xf[4];
    #pragma unroll
    for (int kt = 0; kt < 4; ++kt)
        xf[kt] = *(const short8*)&xdt[ptt*32 + l31][kt*16 + hi*8];

    f32x16 accA, accB;
    #pragma unroll
    for (int r = 0; r < 16; ++r) { accA[r] = 0.f; accB[r] = 0.f; }
    #pragma unroll
    for (int kt = 0; kt < 4; ++kt)
        accA = __builtin_amdgcn_mfma_f32_32x32x16_bf16(wfA[kt], xf[kt], accA, 0, 0, 0);
    if (hasB) {
        #pragma unroll
        for (int kt = 0; kt < 4; ++kt)
            accB = __builtin_amdgcn_mfma_f32_32x32x16_bf16(wfB[kt], xf[kt], accB, 0, 0, 0);
    }

    // ---- epilogue: bias + store Q/K/VP ----
    const int i = ptg*64 + ptt*32 + l31;   // batch-local point
    auto emit = [&](int oct, const f32x16& acc) {
        #pragma unroll
        for (int r = 0; r < 16; ++r) {
            const int row = (r&3) + 8*(r>>2) + 4*hi;
            const int oc  = oct*32 + row;
            if (oc >= 80) continue;
            __hip_bfloat16 h = __float2bfloat16(acc[r] + sbias[oc]);
            if (oc < 8)       Qo[((size_t)b*NPIX + i)*8 + oc]     = h;
            else if (oc < 16) Ko[((size_t)b*NPIX + i)*8 + (oc-8)] = h;
            else {
                const int c  = oc - 16;
                const int chg = i >> 5, s1 = (i>>4)&1, h2 = (i>>3)&1, el = i&7;
                const int ct = c >> 5;
                VPo[(((size_t)b*512 + (size_t)((chg*2 + s1)*2 + ct))*512)
                    + (h2*32 + (c&31))*8 + el] = h;
            }
        }
    };
    emit(octA, accA);
    if (hasB) emit(1, accB);
}

// ---------------------------------------------------------------------------
// Kernel 2: flash attention. 1024 blocks (xcd-mapped: b = blk&7), 256 thr =
// 4 waves = 4 kv-quarters; each block covers 32 queries.
//   S^T = mfma(K_frag, Q_frag): lane (q=l&31) holds 16 of 32 kv scores.
//   PV  = mfma(V_frag(A, packed coalesced), P_frag(B via half-exchange)):
//         D[row=c][col=q], all 16 acc values belong to lane's own query.
// 4-way kv merge through LDS at the end.
// ---------------------------------------------------------------------------
__global__ __launch_bounds__(256, 4) void attn_kernel(
    const __hip_bfloat16* __restrict__ Q, const __hip_bfloat16* __restrict__ K,
    const __hip_bfloat16* __restrict__ VP, float* __restrict__ OS)
{
    const int bb   = blockIdx.x;
    const int b    = bb & 7;          // XCD-locality: batch per XCD
    const int qg   = bb >> 3;         // 0..127
    const int i0   = qg * 32;
    const int t    = threadIdx.x;
    const int lane = t & 63;
    const int kvq  = t >> 6;          // wave = kv quarter
    const int l31  = lane & 31;
    const int hi   = lane >> 5;

    __shared__ float tiles[4][64][33];
    __shared__ float ml[4][2][32];
    __shared__ float fs[4][32];
    __shared__ float ils[32];

    // Q fragment (B operand): hi=0 lanes hold Q[q=i0+l31][d=0..7], hi=1 zero
    U4S8 qf;
    if (hi == 0) qf.u = *(const uint4*)(Q + ((size_t)b*NPIX + i0 + l31)*8);
    else         qf.u = make_uint4(0,0,0,0);

    f32x16 acc0, acc1, zacc;
    #pragma unroll
    for (int r = 0; r < 16; ++r) { acc0[r] = 0.f; acc1[r] = 0.f; zacc[r] = 0.f; }
    float m = -1e30f, l = 0.f;

    const __hip_bfloat16* Kb  = K  + (size_t)b*NPIX*8;
    const __hip_bfloat16* VPb = VP + (size_t)b*512*512;   // 512 frags x 512 bf16

    auto ldK = [&](int kv) {
        U4S8 r;
        if (hi == 0) r.u = *(const uint4*)(Kb + (size_t)(kv + l31)*8);
        else         r.u = make_uint4(0,0,0,0);
        return r;
    };
    auto ldVP = [&](int chg, int s1, int ct) {
        U4S8 r;
        r.u = *(const uint4*)(VPb + ((size_t)((chg*2 + s1)*2 + ct))*512 + lane*8);
        return r;
    };

    int kv0 = kvq * 1024;
    // prefetch chunk 0
    U4S8 kf = ldK(kv0);
    U4S8 v00 = ldVP(kv0>>5, 0, 0), v10 = ldVP(kv0>>5, 0, 1);
    U4S8 v01 = ldVP(kv0>>5, 1, 0), v11 = ldVP(kv0>>5, 1, 1);

    #pragma unroll 1
    for (int ch = 0; ch < 32; ++ch) {
        U4S8 ckf = kf, cv00 = v00, cv01 = v01, cv10 = v10, cv11 = v11;
        const int nkv0 = kv0 + 32;
        // prefetch next chunk (reads past quarter stay inside d_ws; unused on last iter)
        kf  = ldK(nkv0);
        v00 = ldVP(nkv0>>5, 0, 0); v10 = ldVP(nkv0>>5, 0, 1);
        v01 = ldVP(nkv0>>5, 1, 0); v11 = ldVP(nkv0>>5, 1, 1);

        // S^T: lane holds q=l31, kv rows (r&3)+8*(r>>2)+4*hi of this 32-chunk
        f32x16 s = __builtin_amdgcn_mfma_f32_32x32x16_bf16(ckf.s, qf.s, zacc, 0, 0, 0);

        float mx = fmaxf(s[0], s[1]);
        #pragma unroll
        for (int r = 2; r < 16; ++r) mx = fmaxf(mx, s[r]);
        mx = fmaxf(mx, __shfl_xor(mx, 32));

        // deferred rescale (T13): all acc cols are lane's own query -> plain scale
        if (!__all(mx <= m + 8.f)) {
            float mnew = fmaxf(m, mx);
            float sc = __expf(m - mnew);
            l *= sc; m = mnew;
            #pragma unroll
            for (int r = 0; r < 16; ++r) { acc0[r] *= sc; acc1[r] *= sc; }
        }

        float p[16];
        float ssum = 0.f;
        #pragma unroll
        for (int r = 0; r < 16; ++r) { p[r] = __expf(s[r] - m); ssum += p[r]; }
        ssum += __shfl_xor(ssum, 32);
        l += ssum;

        // B-operand P fragments: lane (l31,hi) needs P[q=l31][kv=16s+8hi+j].
        // Own p[] holds kv {4hi+0..3, 8+4hi+0..3, 16+..., 24+...}; partner half
        // supplies the other quads via shfl_xor(32).
        uint32_t W01 = pk2bf(p[0],  p[1]),  W23 = pk2bf(p[2],  p[3]);
        uint32_t W45 = pk2bf(p[4],  p[5]),  W67 = pk2bf(p[6],  p[7]);
        uint32_t W89 = pk2bf(p[8],  p[9]),  Wab = pk2bf(p[10], p[11]);
        uint32_t Wcd = pk2bf(p[12], p[13]), Wef = pk2bf(p[14], p[15]);
        uint32_t W45p = (uint32_t)__shfl_xor((int)W45, 32);
        uint32_t W67p = (uint32_t)__shfl_xor((int)W67, 32);
        uint32_t W01p = (uint32_t)__shfl_xor((int)W01, 32);
        uint32_t W23p = (uint32_t)__shfl_xor((int)W23, 32);
        uint32_t Wcdp = (uint32_t)__shfl_xor((int)Wcd, 32);
        uint32_t Wefp = (uint32_t)__shfl_xor((int)Wef, 32);
        uint32_t W89p = (uint32_t)__shfl_xor((int)W89, 32);
        uint32_t Wabp = (uint32_t)__shfl_xor((int)Wab, 32);
        U4S8 pb0, pb1;
        pb0.u.x = hi ? W45p : W01;   pb0.u.y = hi ? W67p : W23;
        pb0.u.z = hi ? W45  : W01p;  pb0.u.w = hi ? W67  : W23p;
        pb1.u.x = hi ? Wcdp : W89;   pb1.u.y = hi ? Wefp : Wab;
        pb1.u.z = hi ? Wcd  : W89p;  pb1.u.w = hi ? Wef  : Wabp;

        acc0 = __builtin_amdgcn_mfma_f32_32x32x16_bf16(cv00.s, pb0.s, acc0, 0, 0, 0);
        acc1 = __builtin_amdgcn_mfma_f32_32x32x16_bf16(cv10.s, pb0.s, acc1, 0, 0, 0);
        acc0 = __builtin_amdgcn_mfma_f32_32x32x16_bf16(cv01.s, pb1.s, acc0, 0, 0, 0);
        acc1 = __builtin_amdgcn_mfma_f32_32x32x16_bf16(cv11.s, pb1.s, acc1, 0, 0, 0);

        kv0 = nkv0;
    }

    // ---- 4-way kv merge ----
    #pragma unroll
    for (int r = 0; r < 16; ++r) {
        const int cr = (r&3) + 8*(r>>2) + 4*hi;
        tiles[kvq][cr]     [l31] = acc0[r];
        tiles[kvq][cr + 32][l31] = acc1[r];
    }
    if (hi == 0) { ml[kvq][0][l31] = m; ml[kvq][1][l31] = l; }
    __syncthreads();

    if (t < 32) {
        float m0 = ml[0][0][t], m1 = ml[1][0][t], m2 = ml[2][0][t], m3 = ml[3][0][t];
        float ms = fmaxf(fmaxf(m0, m1), fmaxf(m2, m3));
        float f0 = __expf(m0-ms), f1 = __expf(m1-ms), f2 = __expf(m2-ms), f3 = __expf(m3-ms);
        fs[0][t] = f0; fs[1][t] = f1; fs[2][t] = f2; fs[3][t] = f3;
        ils[t] = 1.f / (ml[0][1][t]*f0 + ml[1][1][t]*f1 + ml[2][1][t]*f2 + ml[3][1][t]*f3);
    }
    __syncthreads();

    // combine + write: OS (b, c, n); thread -> (c = t>>2, 8 queries)
    float* outp = OS + (size_t)b*CCH*NPIX + i0;
    const int c  = t >> 2;
    const int q8 = (t & 3) * 8;
    float o[8];
    #pragma unroll
    for (int j = 0; j < 8; ++j) {
        const int q = q8 + j;
        float v = tiles[0][c][q]*fs[0][q] + tiles[1][c][q]*fs[1][q]
                + tiles[2][c][q]*fs[2][q] + tiles[3][c][q]*fs[3][q];
        o[j] = v * ils[q];
    }
    *(float4*)(outp + (size_t)c*NPIX + q8)     = make_float4(o[0], o[1], o[2], o[3]);
    *(float4*)(outp + (size_t)c*NPIX + q8 + 4) = make_float4(o[4], o[5], o[6], o[7]);
}

// ---------------------------------------------------------------------------
// Kernel 3: bilinear x4 upsample (align_corners=True) + gamma*up + x
// ---------------------------------------------------------------------------
__global__ __launch_bounds__(256) void upsample_add_kernel(
    const float* __restrict__ OS, const float* __restrict__ x,
    const float* __restrict__ gamma, float* __restrict__ out)
{
    const size_t idx = (size_t)blockIdx.x * 256 + threadIdx.x;
    const float g = gamma[0];
    const int w  = idx & 255;
    const int h  = (int)((idx >> 8) & 255);
    const size_t bc = idx >> 16;

    const float scale = 63.0f / 255.0f;
    float fh = h * scale; int h0 = (int)fh; float fy = fh - (float)h0; int h1 = min(h0+1, 63);
    float fw = w * scale; int w0 = (int)fw; float fx = fw - (float)w0; int w1 = min(w0+1, 63);

    const float* osp = OS + bc * (size_t)NPIX;
    float v00 = osp[h0*64+w0], v01 = osp[h0*64+w1];
    float v10 = osp[h1*64+w0], v11 = osp[h1*64+w1];
    float vt = v00 + (v01 - v00) * fx;
    float vb = v10 + (v11 - v10) * fx;
    float up = vt + (vb - vt) * fy;
    out[idx] = g * up + x[idx];
}

// ---------------------------------------------------------------------------
extern "C" void kernel_launch(void* const* d_in, const int* in_sizes, int n_in,
                              void* d_out, int out_size, void* d_ws, size_t ws_size,
                              hipStream_t stream) {
    const float* x     = (const float*)d_in[0];
    const float* Wq    = (const float*)d_in[1];
    const float* bq    = (const float*)d_in[2];
    const float* Wk    = (const float*)d_in[3];
    const float* bk    = (const float*)d_in[4];
    const float* Wv    = (const float*)d_in[5];
    const float* bv    = (const float*)d_in[6];
    const float* gamma = (const float*)d_in[7];
    float* out = (float*)d_out;

    char* ws = (char*)d_ws;
    __hip_bfloat16* Qb = (__hip_bfloat16*)(ws);                      // 512 KB
    __hip_bfloat16* Kb = (__hip_bfloat16*)(ws + (size_t)( 512<<10)); // 512 KB
    __hip_bfloat16* VP = (__hip_bfloat16*)(ws + (size_t)(1024<<10)); // 4 MB packed
    float*          OS = (float*)         (ws + (size_t)(5120<<10)); // 8 MB

    pool_conv_kernel<<<512, 256, 0, stream>>>(x, Wq, bq, Wk, bk, Wv, bv, Qb, Kb, VP);
    attn_kernel<<<1024, 256, 0, stream>>>(Qb, Kb, VP, OS);
    const size_t total = (size_t)8 * 64 * 256 * 256;
    upsample_add_kernel<<<(int)(total / 256), 256, 0, stream>>>(OS, x, gamma, out);
}

// Round 8
// 118.577 us; speedup vs baseline: 1.3623x; 1.1139x over previous
//
#include <hip/hip_runtime.h>
#include <hip/hip_bf16.h>

#define CCH 64      // channels
#define NPIX 4096   // 64*64 pooled points

typedef __attribute__((ext_vector_type(8))) short short8;   // 8 bf16 (4 VGPRs)
typedef __attribute__((ext_vector_type(16))) float f32x16;  // MFMA 32x32 accumulator

union U4S8 { uint4 u; short8 s; };

__device__ inline uint32_t pk2bf(float lo, float hi) {
    __hip_bfloat162 h = __float22bfloat162_rn(make_float2(lo, hi));
    return *reinterpret_cast<uint32_t*>(&h);
}

// ---------------------------------------------------------------------------
// Kernel 1: fused avg-pool 4x4 + 1x1 convs via MFMA, COALESCED epilogue.
// grid = 8 b x 64 pooled-rows = 512 blocks, 256 thr = 4 waves.
// Pool: wave w loads channels w*16..+15 -> LDS xdt[64 pt][72 ch] bf16.
// Conv: 32x32x16 bf16 MFMA (A = W frags from global, B = xdt frags).
// Epilogue: acc -> otile[oc][pt] in LDS, then fully-coalesced emits:
//   Q,K: 1KB contiguous per block;  VP: block's 8 frags are CONSECUTIVE
//   (ids ptg*8..+7) -> two coalesced uint4 stores per thread.
// ---------------------------------------------------------------------------
__global__ __launch_bounds__(256, 2) void pool_conv_kernel(
    const float* __restrict__ x,
    const float* __restrict__ Wq, const float* __restrict__ bq,
    const float* __restrict__ Wk, const float* __restrict__ bk,
    const float* __restrict__ Wv, const float* __restrict__ bv,
    __hip_bfloat16* __restrict__ Qo, __hip_bfloat16* __restrict__ Ko,
    __hip_bfloat16* __restrict__ VPo)
{
    const int blk  = blockIdx.x;
    const int b    = blk >> 6;
    const int ptg  = blk & 63;           // pooled row index
    const int t    = threadIdx.x;
    const int lane = t & 63;
    const int w    = t >> 6;
    const int l31  = lane & 31;
    const int hi   = lane >> 5;

    __shared__ __align__(16) __hip_bfloat16 xdt[64][72];    // [pt][ch]
    __shared__ __align__(16) __hip_bfloat16 otile[80][72];  // [oc][pt]
    __shared__ float sbias[96];

    if (t < 96) {
        float v = 0.f;
        if (t < 8)       v = bq[t];
        else if (t < 16) v = bk[t-8];
        else if (t < 80) v = bv[t-16];
        sbias[t] = v;
    }

    // ---- pooling: lane = pooled col, 4 input rows summed ----
    const float* xbase = x + (size_t)(b*CCH)*65536 + (size_t)(ptg*4)*256 + lane*4;
    #pragma unroll 4
    for (int cc = 0; cc < 16; ++cc) {
        const int c = w*16 + cc;
        const float* xp = xbase + (size_t)c*65536;
        float4 v0 = *(const float4*)(xp);
        float4 v1 = *(const float4*)(xp + 256);
        float4 v2 = *(const float4*)(xp + 512);
        float4 v3 = *(const float4*)(xp + 768);
        float s = (v0.x+v0.y+v0.z+v0.w) + (v1.x+v1.y+v1.z+v1.w)
                + (v2.x+v2.y+v2.z+v2.w) + (v3.x+v3.y+v3.z+v3.w);
        xdt[lane][c] = __float2bfloat16(s * 0.0625f);
    }

    // ---- W fragments (A operand): lane(l31,hi) holds W[oct*32+l31][kt*16+8hi+e]
    const int  ptt  = w & 1;
    const int  octA = (w < 2) ? 0 : 2;
    const bool hasB = (w < 2);           // second oc-tile (oct=1)

    short8 wfA[4], wfB[4];
    auto loadW = [&](int oct, short8* wf) {
        const int row = oct*32 + l31;
        const float* wr = nullptr;
        if (row < 8)       wr = Wq + row*CCH;
        else if (row < 16) wr = Wk + (row-8)*CCH;
        else if (row < 80) wr = Wv + (row-16)*CCH;
        #pragma unroll
        for (int kt = 0; kt < 4; ++kt) {
            U4S8 f;
            if (wr) {
                const int c0 = kt*16 + hi*8;
                float4 a = *(const float4*)(wr + c0);
                float4 d = *(const float4*)(wr + c0 + 4);
                f.u.x = pk2bf(a.x, a.y); f.u.y = pk2bf(a.z, a.w);
                f.u.z = pk2bf(d.x, d.y); f.u.w = pk2bf(d.z, d.w);
            } else {
                f.u = make_uint4(0,0,0,0);
            }
            wf[kt] = f.s;
        }
    };
    loadW(octA, wfA);
    if (hasB) loadW(1, wfB);

    __syncthreads();

    // ---- B fragments from LDS + MFMA ----
    short8 xf[4];
    #pragma unroll
    for (int kt = 0; kt < 4; ++kt)
        xf[kt] = *(const short8*)&xdt[ptt*32 + l31][kt*16 + hi*8];

    f32x16 accA, accB;
    #pragma unroll
    for (int r = 0; r < 16; ++r) { accA[r] = 0.f; accB[r] = 0.f; }
    #pragma unroll
    for (int kt = 0; kt < 4; ++kt)
        accA = __builtin_amdgcn_mfma_f32_32x32x16_bf16(wfA[kt], xf[kt], accA, 0, 0, 0);
    if (hasB) {
        #pragma unroll
        for (int kt = 0; kt < 4; ++kt)
            accB = __builtin_amdgcn_mfma_f32_32x32x16_bf16(wfB[kt], xf[kt], accB, 0, 0, 0);
    }

    // ---- epilogue stage 1: acc (+bias) -> otile[oc][pt] ----
    {
        const int pt = ptt*32 + l31;
        #pragma unroll
        for (int r = 0; r < 16; ++r) {
            const int row = (r&3) + 8*(r>>2) + 4*hi;
            const int oc  = octA*32 + row;
            if (oc < 80) otile[oc][pt] = __float2bfloat16(accA[r] + sbias[oc]);
        }
        if (hasB) {
            #pragma unroll
            for (int r = 0; r < 16; ++r) {
                const int row = (r&3) + 8*(r>>2) + 4*hi;
                const int oc  = 32 + row;
                otile[oc][pt] = __float2bfloat16(accB[r] + sbias[oc]);
            }
        }
    }
    __syncthreads();

    // ---- epilogue stage 2: coalesced emits ----
    // Q: 1KB (64 pts x 8 oc), K: 1KB
    if (t < 128) {
        const int p = t & 63;
        const int oc0 = (t < 64) ? 0 : 8;
        unsigned short v[8];
        #pragma unroll
        for (int j = 0; j < 8; ++j)
            v[j] = *reinterpret_cast<const unsigned short*>(&otile[oc0 + j][p]);
        uint4 q;
        q.x = (uint32_t)v[0] | ((uint32_t)v[1] << 16);
        q.y = (uint32_t)v[2] | ((uint32_t)v[3] << 16);
        q.z = (uint32_t)v[4] | ((uint32_t)v[5] << 16);
        q.w = (uint32_t)v[6] | ((uint32_t)v[7] << 16);
        __hip_bfloat16* dst = (t < 64) ? Qo : Ko;
        *(uint4*)(dst + ((size_t)b*NPIX + ptg*64 + p)*8) = q;
    }
    // VP: block's frags = ids ptg*8..+7 (8KB contiguous); o = t*8 and 2048+t*8
    {
        __hip_bfloat16* vdst = VPo + ((size_t)b*512 + (size_t)ptg*8)*512;
        const int c31 = t & 31;
        const int h2  = (t >> 5) & 1;
        const int ct  = (t >> 6) & 1;
        const int s1  = (t >> 7) & 1;
        const int row = 16 + ct*32 + c31;
        const int pt0 = s1*16 + h2*8;
        uint4 u0 = *(const uint4*)&otile[row][pt0];        // a=0
        uint4 u1 = *(const uint4*)&otile[row][pt0 + 32];   // a=1
        *(uint4*)(vdst + t*8)        = u0;
        *(uint4*)(vdst + 2048 + t*8) = u1;
    }
}

// ---------------------------------------------------------------------------
// Kernel 2: flash attention. 1024 blocks (xcd-mapped: b = blk&7), 256 thr =
// 4 waves = 4 kv-quarters; each block covers 32 queries.
//   S^T = mfma(K_frag, Q_frag): lane (q=l&31) holds 16 of 32 kv scores.
//   PV  = mfma(V_frag(A, packed coalesced), P_frag(B via half-exchange)):
//         D[row=c][col=q], all 16 acc values belong to lane's own query.
// 4-way kv merge through LDS at the end.
// ---------------------------------------------------------------------------
__global__ __launch_bounds__(256, 4) void attn_kernel(
    const __hip_bfloat16* __restrict__ Q, const __hip_bfloat16* __restrict__ K,
    const __hip_bfloat16* __restrict__ VP, float* __restrict__ OS)
{
    const int bb   = blockIdx.x;
    const int b    = bb & 7;          // XCD-locality: batch per XCD
    const int qg   = bb >> 3;         // 0..127
    const int i0   = qg * 32;
    const int t    = threadIdx.x;
    const int lane = t & 63;
    const int kvq  = t >> 6;          // wave = kv quarter
    const int l31  = lane & 31;
    const int hi   = lane >> 5;

    __shared__ float tiles[4][64][33];
    __shared__ float ml[4][2][32];
    __shared__ float fs[4][32];
    __shared__ float ils[32];

    // Q fragment (B operand): hi=0 lanes hold Q[q=i0+l31][d=0..7], hi=1 zero
    U4S8 qf;
    if (hi == 0) qf.u = *(const uint4*)(Q + ((size_t)b*NPIX + i0 + l31)*8);
    else         qf.u = make_uint4(0,0,0,0);

    f32x16 acc0, acc1, zacc;
    #pragma unroll
    for (int r = 0; r < 16; ++r) { acc0[r] = 0.f; acc1[r] = 0.f; zacc[r] = 0.f; }
    float m = -1e30f, l = 0.f;

    const __hip_bfloat16* Kb  = K  + (size_t)b*NPIX*8;
    const __hip_bfloat16* VPb = VP + (size_t)b*512*512;   // 512 frags x 512 bf16

    auto ldK = [&](int kv) {
        U4S8 r;
        if (hi == 0) r.u = *(const uint4*)(Kb + (size_t)(kv + l31)*8);
        else         r.u = make_uint4(0,0,0,0);
        return r;
    };
    auto ldVP = [&](int chg, int s1, int ct) {
        U4S8 r;
        r.u = *(const uint4*)(VPb + ((size_t)((chg*2 + s1)*2 + ct))*512 + lane*8);
        return r;
    };

    int kv0 = kvq * 1024;
    // prefetch chunk 0
    U4S8 kf = ldK(kv0);
    U4S8 v00 = ldVP(kv0>>5, 0, 0), v10 = ldVP(kv0>>5, 0, 1);
    U4S8 v01 = ldVP(kv0>>5, 1, 0), v11 = ldVP(kv0>>5, 1, 1);

    #pragma unroll 1
    for (int ch = 0; ch < 32; ++ch) {
        U4S8 ckf = kf, cv00 = v00, cv01 = v01, cv10 = v10, cv11 = v11;
        const int nkv0 = kv0 + 32;
        // prefetch next chunk (reads past quarter stay inside d_ws; unused on last iter)
        kf  = ldK(nkv0);
        v00 = ldVP(nkv0>>5, 0, 0); v10 = ldVP(nkv0>>5, 0, 1);
        v01 = ldVP(nkv0>>5, 1, 0); v11 = ldVP(nkv0>>5, 1, 1);

        // S^T: lane holds q=l31, kv rows (r&3)+8*(r>>2)+4*hi of this 32-chunk
        f32x16 s = __builtin_amdgcn_mfma_f32_32x32x16_bf16(ckf.s, qf.s, zacc, 0, 0, 0);

        float mx = fmaxf(s[0], s[1]);
        #pragma unroll
        for (int r = 2; r < 16; ++r) mx = fmaxf(mx, s[r]);
        mx = fmaxf(mx, __shfl_xor(mx, 32));

        // deferred rescale (T13): all acc cols are lane's own query -> plain scale
        if (!__all(mx <= m + 8.f)) {
            float mnew = fmaxf(m, mx);
            float sc = __expf(m - mnew);
            l *= sc; m = mnew;
            #pragma unroll
            for (int r = 0; r < 16; ++r) { acc0[r] *= sc; acc1[r] *= sc; }
        }

        float p[16];
        float ssum = 0.f;
        #pragma unroll
        for (int r = 0; r < 16; ++r) { p[r] = __expf(s[r] - m); ssum += p[r]; }
        ssum += __shfl_xor(ssum, 32);
        l += ssum;

        // B-operand P fragments: lane (l31,hi) needs P[q=l31][kv=16s+8hi+j].
        // Own p[] holds kv {4hi+0..3, 8+4hi+0..3, 16+..., 24+...}; partner half
        // supplies the other quads via shfl_xor(32).
        uint32_t W01 = pk2bf(p[0],  p[1]),  W23 = pk2bf(p[2],  p[3]);
        uint32_t W45 = pk2bf(p[4],  p[5]),  W67 = pk2bf(p[6],  p[7]);
        uint32_t W89 = pk2bf(p[8],  p[9]),  Wab = pk2bf(p[10], p[11]);
        uint32_t Wcd = pk2bf(p[12], p[13]), Wef = pk2bf(p[14], p[15]);
        uint32_t W45p = (uint32_t)__shfl_xor((int)W45, 32);
        uint32_t W67p = (uint32_t)__shfl_xor((int)W67, 32);
        uint32_t W01p = (uint32_t)__shfl_xor((int)W01, 32);
        uint32_t W23p = (uint32_t)__shfl_xor((int)W23, 32);
        uint32_t Wcdp = (uint32_t)__shfl_xor((int)Wcd, 32);
        uint32_t Wefp = (uint32_t)__shfl_xor((int)Wef, 32);
        uint32_t W89p = (uint32_t)__shfl_xor((int)W89, 32);
        uint32_t Wabp = (uint32_t)__shfl_xor((int)Wab, 32);
        U4S8 pb0, pb1;
        pb0.u.x = hi ? W45p : W01;   pb0.u.y = hi ? W67p : W23;
        pb0.u.z = hi ? W45  : W01p;  pb0.u.w = hi ? W67  : W23p;
        pb1.u.x = hi ? Wcdp : W89;   pb1.u.y = hi ? Wefp : Wab;
        pb1.u.z = hi ? Wcd  : W89p;  pb1.u.w = hi ? Wef  : Wabp;

        acc0 = __builtin_amdgcn_mfma_f32_32x32x16_bf16(cv00.s, pb0.s, acc0, 0, 0, 0);
        acc1 = __builtin_amdgcn_mfma_f32_32x32x16_bf16(cv10.s, pb0.s, acc1, 0, 0, 0);
        acc0 = __builtin_amdgcn_mfma_f32_32x32x16_bf16(cv01.s, pb1.s, acc0, 0, 0, 0);
        acc1 = __builtin_amdgcn_mfma_f32_32x32x16_bf16(cv11.s, pb1.s, acc1, 0, 0, 0);

        kv0 = nkv0;
    }

    // ---- 4-way kv merge ----
    #pragma unroll
    for (int r = 0; r < 16; ++r) {
        const int cr = (r&3) + 8*(r>>2) + 4*hi;
        tiles[kvq][cr]     [l31] = acc0[r];
        tiles[kvq][cr + 32][l31] = acc1[r];
    }
    if (hi == 0) { ml[kvq][0][l31] = m; ml[kvq][1][l31] = l; }
    __syncthreads();

    if (t < 32) {
        float m0 = ml[0][0][t], m1 = ml[1][0][t], m2 = ml[2][0][t], m3 = ml[3][0][t];
        float ms = fmaxf(fmaxf(m0, m1), fmaxf(m2, m3));
        float f0 = __expf(m0-ms), f1 = __expf(m1-ms), f2 = __expf(m2-ms), f3 = __expf(m3-ms);
        fs[0][t] = f0; fs[1][t] = f1; fs[2][t] = f2; fs[3][t] = f3;
        ils[t] = 1.f / (ml[0][1][t]*f0 + ml[1][1][t]*f1 + ml[2][1][t]*f2 + ml[3][1][t]*f3);
    }
    __syncthreads();

    // combine + write: OS (b, c, n); thread -> (c = t>>2, 8 queries)
    float* outp = OS + (size_t)b*CCH*NPIX + i0;
    const int c  = t >> 2;
    const int q8 = (t & 3) * 8;
    float o[8];
    #pragma unroll
    for (int j = 0; j < 8; ++j) {
        const int q = q8 + j;
        float v = tiles[0][c][q]*fs[0][q] + tiles[1][c][q]*fs[1][q]
                + tiles[2][c][q]*fs[2][q] + tiles[3][c][q]*fs[3][q];
        o[j] = v * ils[q];
    }
    *(float4*)(outp + (size_t)c*NPIX + q8)     = make_float4(o[0], o[1], o[2], o[3]);
    *(float4*)(outp + (size_t)c*NPIX + q8 + 4) = make_float4(o[4], o[5], o[6], o[7]);
}

// ---------------------------------------------------------------------------
// Kernel 3: bilinear x4 upsample (align_corners=True) + gamma*up + x,
// float4-vectorized (4 outputs/thread share h-row).
// ---------------------------------------------------------------------------
__global__ __launch_bounds__(256) void upsample_add_kernel(
    const float* __restrict__ OS, const float* __restrict__ x,
    const float* __restrict__ gamma, float* __restrict__ out)
{
    const size_t qidx = (size_t)blockIdx.x * 256 + threadIdx.x;  // float4 index
    const size_t idx  = qidx * 4;
    const float g = gamma[0];
    const int w4 = (int)(idx & 255);
    const int h  = (int)((idx >> 8) & 255);
    const size_t bc = idx >> 16;

    const float scale = 63.0f / 255.0f;
    float fh = h * scale; int h0 = (int)fh; float fy = fh - (float)h0; int h1 = min(h0+1, 63);

    const float* r0 = OS + bc * (size_t)NPIX + h0*64;
    const float* r1 = OS + bc * (size_t)NPIX + h1*64;
    float4 xi = *(const float4*)(x + idx);

    float o[4];
    #pragma unroll
    for (int j = 0; j < 4; ++j) {
        const int w = w4 + j;
        float fw = w * scale; int w0 = (int)fw; float fx = fw - (float)w0; int w1 = min(w0+1, 63);
        float a0 = r0[w0], a1 = r0[w1], b0 = r1[w0], b1 = r1[w1];
        float vt = a0 + (a1 - a0) * fx;
        float vb = b0 + (b1 - b0) * fx;
        o[j] = vt + (vb - vt) * fy;
    }
    float4 ov;
    ov.x = g*o[0] + xi.x; ov.y = g*o[1] + xi.y;
    ov.z = g*o[2] + xi.z; ov.w = g*o[3] + xi.w;
    *(float4*)(out + idx) = ov;
}

// ---------------------------------------------------------------------------
extern "C" void kernel_launch(void* const* d_in, const int* in_sizes, int n_in,
                              void* d_out, int out_size, void* d_ws, size_t ws_size,
                              hipStream_t stream) {
    const float* x     = (const float*)d_in[0];
    const float* Wq    = (const float*)d_in[1];
    const float* bq    = (const float*)d_in[2];
    const float* Wk    = (const float*)d_in[3];
    const float* bk    = (const float*)d_in[4];
    const float* Wv    = (const float*)d_in[5];
    const float* bv    = (const float*)d_in[6];
    const float* gamma = (const float*)d_in[7];
    float* out = (float*)d_out;

    char* ws = (char*)d_ws;
    __hip_bfloat16* Qb = (__hip_bfloat16*)(ws);                      // 512 KB
    __hip_bfloat16* Kb = (__hip_bfloat16*)(ws + (size_t)( 512<<10)); // 512 KB
    __hip_bfloat16* VP = (__hip_bfloat16*)(ws + (size_t)(1024<<10)); // 4 MB packed
    float*          OS = (float*)         (ws + (size_t)(5120<<10)); // 8 MB

    pool_conv_kernel<<<512, 256, 0, stream>>>(x, Wq, bq, Wk, bk, Wv, bv, Qb, Kb, VP);
    attn_kernel<<<1024, 256, 0, stream>>>(Qb, Kb, VP, OS);
    const size_t total4 = (size_t)8 * 64 * 256 * 256 / 4;
    upsample_add_kernel<<<(int)(total4 / 256), 256, 0, stream>>>(OS, x, gamma, out);
}

// Round 9
// 115.105 us; speedup vs baseline: 1.4034x; 1.0302x over previous
//
#include <hip/hip_runtime.h>
#include <hip/hip_bf16.h>

#define CCH 64      // channels
#define NPIX 4096   // 64*64 pooled points

typedef __attribute__((ext_vector_type(8))) short short8;   // 8 bf16 (4 VGPRs)
typedef __attribute__((ext_vector_type(16))) float f32x16;  // MFMA 32x32 accumulator

union U4S8 { uint4 u; short8 s; };

__device__ inline uint32_t pk2bf(float lo, float hi) {
    __hip_bfloat162 h = __float22bfloat162_rn(make_float2(lo, hi));
    return *reinterpret_cast<uint32_t*>(&h);
}

// ---------------------------------------------------------------------------
// Kernel 1: fused avg-pool 4x4 + 1x1 convs via MFMA, coalesced epilogue.
// VP is packed with the PV kv-permutation sigma: within each 16-k MFMA step,
//   k-rows 8*hi+j  hold kv = 16*s + (j<4 ? j : j+4) + 4*hi + (j>=4 ? 4*hi : 0)
//   i.e. hi=0 rows take kv {0-3,8-11}, hi=1 rows take {4-7,12-15}.
// This makes attn's P B-fragments pure in-lane cvt_pk packs (no shuffles).
// ---------------------------------------------------------------------------
__global__ __launch_bounds__(256, 2) void pool_conv_kernel(
    const float* __restrict__ x,
    const float* __restrict__ Wq, const float* __restrict__ bq,
    const float* __restrict__ Wk, const float* __restrict__ bk,
    const float* __restrict__ Wv, const float* __restrict__ bv,
    __hip_bfloat16* __restrict__ Qo, __hip_bfloat16* __restrict__ Ko,
    __hip_bfloat16* __restrict__ VPo)
{
    const int blk  = blockIdx.x;
    const int b    = blk >> 6;
    const int ptg  = blk & 63;           // pooled row index
    const int t    = threadIdx.x;
    const int lane = t & 63;
    const int w    = t >> 6;
    const int l31  = lane & 31;
    const int hi   = lane >> 5;

    __shared__ __align__(16) __hip_bfloat16 xdt[64][72];    // [pt][ch]
    __shared__ __align__(16) __hip_bfloat16 otile[80][72];  // [oc][pt]
    __shared__ float sbias[96];

    if (t < 96) {
        float v = 0.f;
        if (t < 8)       v = bq[t];
        else if (t < 16) v = bk[t-8];
        else if (t < 80) v = bv[t-16];
        sbias[t] = v;
    }

    // ---- pooling: lane = pooled col, 4 input rows summed ----
    const float* xbase = x + (size_t)(b*CCH)*65536 + (size_t)(ptg*4)*256 + lane*4;
    #pragma unroll
    for (int cc = 0; cc < 16; ++cc) {
        const int c = w*16 + cc;
        const float* xp = xbase + (size_t)c*65536;
        float4 v0 = *(const float4*)(xp);
        float4 v1 = *(const float4*)(xp + 256);
        float4 v2 = *(const float4*)(xp + 512);
        float4 v3 = *(const float4*)(xp + 768);
        float s = (v0.x+v0.y+v0.z+v0.w) + (v1.x+v1.y+v1.z+v1.w)
                + (v2.x+v2.y+v2.z+v2.w) + (v3.x+v3.y+v3.z+v3.w);
        xdt[lane][c] = __float2bfloat16(s * 0.0625f);
    }

    // ---- W fragments (A operand): lane(l31,hi) holds W[oct*32+l31][kt*16+8hi+e]
    const int  ptt  = w & 1;
    const int  octA = (w < 2) ? 0 : 2;
    const bool hasB = (w < 2);           // second oc-tile (oct=1)

    short8 wfA[4], wfB[4];
    auto loadW = [&](int oct, short8* wf) {
        const int row = oct*32 + l31;
        const float* wr = nullptr;
        if (row < 8)       wr = Wq + row*CCH;
        else if (row < 16) wr = Wk + (row-8)*CCH;
        else if (row < 80) wr = Wv + (row-16)*CCH;
        #pragma unroll
        for (int kt = 0; kt < 4; ++kt) {
            U4S8 f;
            if (wr) {
                const int c0 = kt*16 + hi*8;
                float4 a = *(const float4*)(wr + c0);
                float4 d = *(const float4*)(wr + c0 + 4);
                f.u.x = pk2bf(a.x, a.y); f.u.y = pk2bf(a.z, a.w);
                f.u.z = pk2bf(d.x, d.y); f.u.w = pk2bf(d.z, d.w);
            } else {
                f.u = make_uint4(0,0,0,0);
            }
            wf[kt] = f.s;
        }
    };
    loadW(octA, wfA);
    if (hasB) loadW(1, wfB);

    __syncthreads();

    // ---- B fragments from LDS + MFMA ----
    short8 xf[4];
    #pragma unroll
    for (int kt = 0; kt < 4; ++kt)
        xf[kt] = *(const short8*)&xdt[ptt*32 + l31][kt*16 + hi*8];

    f32x16 accA, accB;
    #pragma unroll
    for (int r = 0; r < 16; ++r) { accA[r] = 0.f; accB[r] = 0.f; }
    #pragma unroll
    for (int kt = 0; kt < 4; ++kt)
        accA = __builtin_amdgcn_mfma_f32_32x32x16_bf16(wfA[kt], xf[kt], accA, 0, 0, 0);
    if (hasB) {
        #pragma unroll
        for (int kt = 0; kt < 4; ++kt)
            accB = __builtin_amdgcn_mfma_f32_32x32x16_bf16(wfB[kt], xf[kt], accB, 0, 0, 0);
    }

    // ---- epilogue stage 1: acc (+bias) -> otile[oc][pt] ----
    {
        const int pt = ptt*32 + l31;
        #pragma unroll
        for (int r = 0; r < 16; ++r) {
            const int row = (r&3) + 8*(r>>2) + 4*hi;
            const int oc  = octA*32 + row;
            if (oc < 80) otile[oc][pt] = __float2bfloat16(accA[r] + sbias[oc]);
        }
        if (hasB) {
            #pragma unroll
            for (int r = 0; r < 16; ++r) {
                const int row = (r&3) + 8*(r>>2) + 4*hi;
                const int oc  = 32 + row;
                otile[oc][pt] = __float2bfloat16(accB[r] + sbias[oc]);
            }
        }
    }
    __syncthreads();

    // ---- epilogue stage 2: coalesced emits ----
    // Q: 1KB (64 pts x 8 oc), K: 1KB
    if (t < 128) {
        const int p = t & 63;
        const int oc0 = (t < 64) ? 0 : 8;
        unsigned short v[8];
        #pragma unroll
        for (int j = 0; j < 8; ++j)
            v[j] = *reinterpret_cast<const unsigned short*>(&otile[oc0 + j][p]);
        uint4 q;
        q.x = (uint32_t)v[0] | ((uint32_t)v[1] << 16);
        q.y = (uint32_t)v[2] | ((uint32_t)v[3] << 16);
        q.z = (uint32_t)v[4] | ((uint32_t)v[5] << 16);
        q.w = (uint32_t)v[6] | ((uint32_t)v[7] << 16);
        __hip_bfloat16* dst = (t < 64) ? Qo : Ko;
        *(uint4*)(dst + ((size_t)b*NPIX + ptg*64 + p)*8) = q;
    }
    // VP with sigma-permuted element order: lane(c31,h2) element j holds
    //   V[c][base + (h2=0: {0-3,8-11}[j]) | (h2=1: {4-7,12-15}[j])]
    {
        __hip_bfloat16* vdst = VPo + ((size_t)b*512 + (size_t)ptg*8)*512;
        const int c31 = t & 31;
        const int h2  = (t >> 5) & 1;
        const int ct  = (t >> 6) & 1;
        const int s1  = (t >> 7) & 1;
        const int row = 16 + ct*32 + c31;
        const int pt0 = s1*16 + h2*4;
        uint2 a0 = *(const uint2*)&otile[row][pt0];         // a=0, j=0..3
        uint2 a1 = *(const uint2*)&otile[row][pt0 + 8];     // a=0, j=4..7
        uint2 b0 = *(const uint2*)&otile[row][pt0 + 32];    // a=1, j=0..3
        uint2 b1 = *(const uint2*)&otile[row][pt0 + 40];    // a=1, j=4..7
        *(uint4*)(vdst + t*8)        = make_uint4(a0.x, a0.y, a1.x, a1.y);
        *(uint4*)(vdst + 2048 + t*8) = make_uint4(b0.x, b0.y, b1.x, b1.y);
    }
}

// ---------------------------------------------------------------------------
// Kernel 2: flash attention. 1024 blocks (xcd-mapped: b = blk&7), 256 thr =
// 4 waves = 4 kv-quarters; each block covers 32 queries.
//   S^T = mfma(K_frag, Q_frag): lane (q=l&31) holds 16 of 32 kv scores.
//   PV  = mfma(V_frag(A, sigma-packed), P_frag(B, pure in-lane packs)):
//         sigma puts each lane's own p[0..7]/p[8..15] exactly at its B rows
//         -> ZERO cross-lane ops for P. D[row=c][col=q], all acc = own query.
// 4-way kv merge through LDS at the end.
// ---------------------------------------------------------------------------
__global__ __launch_bounds__(256, 4) void attn_kernel(
    const __hip_bfloat16* __restrict__ Q, const __hip_bfloat16* __restrict__ K,
    const __hip_bfloat16* __restrict__ VP, float* __restrict__ OS)
{
    const int bb   = blockIdx.x;
    const int b    = bb & 7;          // XCD-locality: batch per XCD
    const int qg   = bb >> 3;         // 0..127
    const int i0   = qg * 32;
    const int t    = threadIdx.x;
    const int lane = t & 63;
    const int kvq  = t >> 6;          // wave = kv quarter
    const int l31  = lane & 31;
    const int hi   = lane >> 5;

    __shared__ float tiles[4][64][33];
    __shared__ float ml[4][2][32];
    __shared__ float fs[4][32];
    __shared__ float ils[32];

    // Q fragment (B operand): hi=0 lanes hold Q[q=i0+l31][d=0..7], hi=1 zero
    U4S8 qf;
    if (hi == 0) qf.u = *(const uint4*)(Q + ((size_t)b*NPIX + i0 + l31)*8);
    else         qf.u = make_uint4(0,0,0,0);

    f32x16 acc0, acc1, zacc;
    #pragma unroll
    for (int r = 0; r < 16; ++r) { acc0[r] = 0.f; acc1[r] = 0.f; zacc[r] = 0.f; }
    float m = -1e30f, l = 0.f;

    const __hip_bfloat16* Kb  = K  + (size_t)b*NPIX*8;
    const __hip_bfloat16* VPb = VP + (size_t)b*512*512;   // 512 frags x 512 bf16

    auto ldK = [&](int kv) {
        U4S8 r;
        if (hi == 0) r.u = *(const uint4*)(Kb + (size_t)(kv + l31)*8);
        else         r.u = make_uint4(0,0,0,0);
        return r;
    };
    auto ldVP = [&](int chg, int s1, int ct) {
        U4S8 r;
        r.u = *(const uint4*)(VPb + ((size_t)((chg*2 + s1)*2 + ct))*512 + lane*8);
        return r;
    };

    int kv0 = kvq * 1024;
    // prefetch chunk 0
    U4S8 kf = ldK(kv0);
    U4S8 v00 = ldVP(kv0>>5, 0, 0), v10 = ldVP(kv0>>5, 0, 1);
    U4S8 v01 = ldVP(kv0>>5, 1, 0), v11 = ldVP(kv0>>5, 1, 1);

    #pragma unroll 1
    for (int ch = 0; ch < 32; ++ch) {
        U4S8 ckf = kf, cv00 = v00, cv01 = v01, cv10 = v10, cv11 = v11;
        const int nkv0 = kv0 + 32;
        // prefetch next chunk (reads past quarter stay inside d_ws; unused on last iter)
        kf  = ldK(nkv0);
        v00 = ldVP(nkv0>>5, 0, 0); v10 = ldVP(nkv0>>5, 0, 1);
        v01 = ldVP(nkv0>>5, 1, 0); v11 = ldVP(nkv0>>5, 1, 1);

        // S^T: lane holds q=l31, kv rows (r&3)+8*(r>>2)+4*hi of this 32-chunk
        f32x16 s = __builtin_amdgcn_mfma_f32_32x32x16_bf16(ckf.s, qf.s, zacc, 0, 0, 0);

        float mx = fmaxf(s[0], s[1]);
        #pragma unroll
        for (int r = 2; r < 16; ++r) mx = fmaxf(mx, s[r]);
        mx = fmaxf(mx, __shfl_xor(mx, 32));

        // deferred rescale (T13): all acc cols are lane's own query -> plain scale
        if (!__all(mx <= m + 8.f)) {
            float mnew = fmaxf(m, mx);
            float sc = __expf(m - mnew);
            l *= sc; m = mnew;
            #pragma unroll
            for (int r = 0; r < 16; ++r) { acc0[r] *= sc; acc1[r] *= sc; }
        }

        float p[16];
        float ssum = 0.f;
        #pragma unroll
        for (int r = 0; r < 16; ++r) { p[r] = __expf(s[r] - m); ssum += p[r]; }
        ssum += __shfl_xor(ssum, 32);
        l += ssum;

        // B-operand P fragments, sigma-matched to VP packing:
        // lane(l31,hi)'s B rows k=8hi+j need exactly own p[0..7] (step 0)
        // and p[8..15] (step 1), in order. Pure cvt_pk, no cross-lane ops.
        U4S8 pb0, pb1;
        pb0.u.x = pk2bf(p[0],  p[1]);  pb0.u.y = pk2bf(p[2],  p[3]);
        pb0.u.z = pk2bf(p[4],  p[5]);  pb0.u.w = pk2bf(p[6],  p[7]);
        pb1.u.x = pk2bf(p[8],  p[9]);  pb1.u.y = pk2bf(p[10], p[11]);
        pb1.u.z = pk2bf(p[12], p[13]); pb1.u.w = pk2bf(p[14], p[15]);

        acc0 = __builtin_amdgcn_mfma_f32_32x32x16_bf16(cv00.s, pb0.s, acc0, 0, 0, 0);
        acc1 = __builtin_amdgcn_mfma_f32_32x32x16_bf16(cv10.s, pb0.s, acc1, 0, 0, 0);
        acc0 = __builtin_amdgcn_mfma_f32_32x32x16_bf16(cv01.s, pb1.s, acc0, 0, 0, 0);
        acc1 = __builtin_amdgcn_mfma_f32_32x32x16_bf16(cv11.s, pb1.s, acc1, 0, 0, 0);

        kv0 = nkv0;
    }

    // ---- 4-way kv merge ----
    #pragma unroll
    for (int r = 0; r < 16; ++r) {
        const int cr = (r&3) + 8*(r>>2) + 4*hi;
        tiles[kvq][cr]     [l31] = acc0[r];
        tiles[kvq][cr + 32][l31] = acc1[r];
    }
    if (hi == 0) { ml[kvq][0][l31] = m; ml[kvq][1][l31] = l; }
    __syncthreads();

    if (t < 32) {
        float m0 = ml[0][0][t], m1 = ml[1][0][t], m2 = ml[2][0][t], m3 = ml[3][0][t];
        float ms = fmaxf(fmaxf(m0, m1), fmaxf(m2, m3));
        float f0 = __expf(m0-ms), f1 = __expf(m1-ms), f2 = __expf(m2-ms), f3 = __expf(m3-ms);
        fs[0][t] = f0; fs[1][t] = f1; fs[2][t] = f2; fs[3][t] = f3;
        ils[t] = 1.f / (ml[0][1][t]*f0 + ml[1][1][t]*f1 + ml[2][1][t]*f2 + ml[3][1][t]*f3);
    }
    __syncthreads();

    // combine + write: OS (b, c, n); thread -> (c = t>>2, 8 queries)
    float* outp = OS + (size_t)b*CCH*NPIX + i0;
    const int c  = t >> 2;
    const int q8 = (t & 3) * 8;
    float o[8];
    #pragma unroll
    for (int j = 0; j < 8; ++j) {
        const int q = q8 + j;
        float v = tiles[0][c][q]*fs[0][q] + tiles[1][c][q]*fs[1][q]
                + tiles[2][c][q]*fs[2][q] + tiles[3][c][q]*fs[3][q];
        o[j] = v * ils[q];
    }
    *(float4*)(outp + (size_t)c*NPIX + q8)     = make_float4(o[0], o[1], o[2], o[3]);
    *(float4*)(outp + (size_t)c*NPIX + q8 + 4) = make_float4(o[4], o[5], o[6], o[7]);
}

// ---------------------------------------------------------------------------
// Kernel 3: bilinear x4 upsample (align_corners=True) + gamma*up + x,
// float4-vectorized (4 outputs/thread share h-row).
// ---------------------------------------------------------------------------
__global__ __launch_bounds__(256) void upsample_add_kernel(
    const float* __restrict__ OS, const float* __restrict__ x,
    const float* __restrict__ gamma, float* __restrict__ out)
{
    const size_t qidx = (size_t)blockIdx.x * 256 + threadIdx.x;  // float4 index
    const size_t idx  = qidx * 4;
    const float g = gamma[0];
    const int w4 = (int)(idx & 255);
    const int h  = (int)((idx >> 8) & 255);
    const size_t bc = idx >> 16;

    const float scale = 63.0f / 255.0f;
    float fh = h * scale; int h0 = (int)fh; float fy = fh - (float)h0; int h1 = min(h0+1, 63);

    const float* r0 = OS + bc * (size_t)NPIX + h0*64;
    const float* r1 = OS + bc * (size_t)NPIX + h1*64;
    float4 xi = *(const float4*)(x + idx);

    float o[4];
    #pragma unroll
    for (int j = 0; j < 4; ++j) {
        const int w = w4 + j;
        float fw = w * scale; int w0 = (int)fw; float fx = fw - (float)w0; int w1 = min(w0+1, 63);
        float a0 = r0[w0], a1 = r0[w1], b0 = r1[w0], b1 = r1[w1];
        float vt = a0 + (a1 - a0) * fx;
        float vb = b0 + (b1 - b0) * fx;
        o[j] = vt + (vb - vt) * fy;
    }
    float4 ov;
    ov.x = g*o[0] + xi.x; ov.y = g*o[1] + xi.y;
    ov.z = g*o[2] + xi.z; ov.w = g*o[3] + xi.w;
    *(float4*)(out + idx) = ov;
}

// ---------------------------------------------------------------------------
extern "C" void kernel_launch(void* const* d_in, const int* in_sizes, int n_in,
                              void* d_out, int out_size, void* d_ws, size_t ws_size,
                              hipStream_t stream) {
    const float* x     = (const float*)d_in[0];
    const float* Wq    = (const float*)d_in[1];
    const float* bq    = (const float*)d_in[2];
    const float* Wk    = (const float*)d_in[3];
    const float* bk    = (const float*)d_in[4];
    const float* Wv    = (const float*)d_in[5];
    const float* bv    = (const float*)d_in[6];
    const float* gamma = (const float*)d_in[7];
    float* out = (float*)d_out;

    char* ws = (char*)d_ws;
    __hip_bfloat16* Qb = (__hip_bfloat16*)(ws);                      // 512 KB
    __hip_bfloat16* Kb = (__hip_bfloat16*)(ws + (size_t)( 512<<10)); // 512 KB
    __hip_bfloat16* VP = (__hip_bfloat16*)(ws + (size_t)(1024<<10)); // 4 MB packed
    float*          OS = (float*)         (ws + (size_t)(5120<<10)); // 8 MB

    pool_conv_kernel<<<512, 256, 0, stream>>>(x, Wq, bq, Wk, bk, Wv, bv, Qb, Kb, VP);
    attn_kernel<<<1024, 256, 0, stream>>>(Qb, Kb, VP, OS);
    const size_t total4 = (size_t)8 * 64 * 256 * 256 / 4;
    upsample_add_kernel<<<(int)(total4 / 256), 256, 0, stream>>>(OS, x, gamma, out);
}